// Round 7
// baseline (518.520 us; speedup 1.0000x reference)
//
#include <hip/hip_runtime.h>

typedef short bf16x8 __attribute__((ext_vector_type(8)));
typedef float f32x4 __attribute__((ext_vector_type(4)));

__device__ __forceinline__ float leaky_f(float z) { return fmaxf(z, 0.2f * z); }
__device__ __forceinline__ unsigned short f2b(float f) {
    unsigned u = __float_as_uint(f);
    return (unsigned short)((u + 0x7fffu + ((u >> 16) & 1u)) >> 16);  // RTNE
}
__device__ __forceinline__ float b2f(unsigned short h) {
    return __uint_as_float(((unsigned)h) << 16);
}

// split-conv stats: replicated 8x (one 512-float slot per XCD L2)
#define STREP 512

// ---------------------------------------------------------------------------
// x [V][4][B=4] fp32 -> bf16 planes [B][V][4]
// ---------------------------------------------------------------------------
__global__ __launch_bounds__(256) void cast_x(const float* __restrict__ x,
                                              unsigned short* __restrict__ out, int V) {
    int idx = blockIdx.x * 256 + threadIdx.x;
    int b = blockIdx.y;
    if (idx < V * 4) out[(size_t)b * V * 4 + idx] = f2b(x[(size_t)idx * 4 + b]);
}

// ---------------------------------------------------------------------------
// All 8 weight prepacks in ONE launch.
// ---------------------------------------------------------------------------
__global__ __launch_bounds__(256) void prepack_all(
    const float* __restrict__ w0, const float* __restrict__ w1,
    const float* __restrict__ w2, const float* __restrict__ w3,
    const float* __restrict__ w4, const float* __restrict__ w5,
    const float* __restrict__ w6, const float* __restrict__ w7,
    unsigned short* __restrict__ WP) {
    int gid = blockIdx.x * 256 + threadIdx.x;  // < 2514944
    const float* W;
    int base, KC, NT;
    if (gid < 3072)        { W = w0; base = 0;       KC = 76;   NT = 2; }
    else if (gid < 22528)  { W = w1; base = 3072;    KC = 608;  NT = 2; }
    else if (gid < 61440)  { W = w2; base = 22528;   KC = 608;  NT = 4; }
    else if (gid < 139264) { W = w3; base = 61440;   KC = 1216; NT = 4; }
    else if (gid < 303104) { W = w4; base = 139264;  KC = 1216; NT = 8; }
    else if (gid < 614400) { W = w5; base = 303104;  KC = 2432; NT = 8; }
    else if (gid < 1269760){ W = w6; base = 614400;  KC = 2432; NT = 16; }
    else                   { W = w7; base = 1269760; KC = 4864; NT = 16; }
    int idx = gid - base;
    int j = idx & 7, lane = (idx >> 3) & 63, q = idx >> 9;
    int nt = q % NT, chunk = q / NT;
    int kc = chunk * 32 + (lane >> 4) * 8 + j;
    int cout = nt * 16 + (lane & 15);
    float v = (kc < KC) ? W[(size_t)cout * KC + kc] : 0.f;
    WP[gid] = f2b(v);
}

// ---------------------------------------------------------------------------
// MFMA conv, batch-pinned-to-XCD (xcd=bid&7, batch=xcd>>1). Block = 4 waves =
// 4 vertex tiles of one batch. Grouped loads + sched_barrier(0) force the
// scheduler to keep GP loads in flight before the MFMA burst (MLP).
// FUSE: bf16 store + per-block partial stats (NO atomics). !FUSE: split-K
// fp32 atomicAdd into zeroed Y.
// ---------------------------------------------------------------------------
template <int CIN, int COUT, int NG, int CPS, int SPLIT, bool FUSE>
__global__ __launch_bounds__(256, 4) void conv_mfma(
    const unsigned short* __restrict__ actb, const int* __restrict__ neigh,
    const unsigned short* __restrict__ wp, void* __restrict__ yout,
    float* __restrict__ opart, int V, int perx) {
    constexpr int LOGC = (CIN == 32) ? 5 : (CIN == 64) ? 6 : (CIN == 128) ? 7 : 8;
    constexpr int NT = COUT / 16;
    constexpr int NGRP = NT / NG;
    constexpr int GP = (NG >= 4) ? 3 : ((CPS < 6) ? CPS : 6);
    __shared__ int shn[4 * 304];
    __shared__ float ss[FUSE ? 2 * COUT : 1];
    const int VT = (V + 15) >> 4;
    const int VT4 = (VT + 3) >> 2;
    const int xcd = blockIdx.x & 7;
    const int b = xcd >> 1;
    const int logical = (xcd & 1) * perx + (blockIdx.x >> 3);
    const int tid = threadIdx.x;
    if (logical >= VT4 * NGRP * SPLIT) {
        if constexpr (FUSE) {   // padding block: zero its partial slot
            float* pb = opart + (size_t)blockIdx.x * (2 * COUT);
            for (int t = tid; t < 2 * COUT; t += 256) pb[t] = 0.f;
        }
        return;
    }
    const int sp = logical % SPLIT;
    const int t1 = logical / SPLIT;
    const int ng = t1 % NGRP;
    const int st = t1 / NGRP;
    const int lane = tid & 63;
    const int wib = tid >> 6;
    const int vt = st * 4 + wib;
    const int vtc = vt < VT ? vt : VT - 1;
    const int v0 = vtc * 16;
    const int m = lane & 15, quad = lane >> 4;
    int* sn = shn + wib * 304;
    {
        const int lim = V * 19 - 1;
        for (int t = lane; t < 304; t += 64) {
            int src = v0 * 19 + t;
            sn[t] = neigh[src < lim ? src : lim];
        }
    }
    if constexpr (FUSE) {
        for (int t = tid; t < 2 * COUT; t += 256) ss[t] = 0.f;
    }
    __syncthreads();

    const unsigned short* plane = actb + (size_t)b * V * CIN;
    const unsigned short* wl = wp + ((size_t)(ng * NG) * 64 + lane) * 8;
    const int c0 = sp * CPS;

    f32x4 acc[NG];
#pragma unroll
    for (int t = 0; t < NG; ++t) acc[t] = (f32x4){0.f, 0.f, 0.f, 0.f};

#pragma unroll
    for (int i0 = 0; i0 < CPS; i0 += GP) {
        bf16x8 a[GP];
        bf16x8 bf[GP][NG];
#pragma unroll
        for (int g = 0; g < GP; ++g) {
            if (i0 + g < CPS) {
                const int ch = c0 + i0 + g;
                int k_nb = (ch * 32) >> LOGC;   // wave-uniform
                k_nb = k_nb < 18 ? k_nb : 18;   // clamp for zero-padded chunks
                const int ci = ((ch * 32) & (CIN - 1)) + quad * 8;
                a[g] = *(const bf16x8*)(plane + (size_t)sn[m * 19 + k_nb] * CIN + ci);
                const unsigned short* wc = wl + (size_t)ch * NT * 512;
#pragma unroll
                for (int t = 0; t < NG; ++t)
                    bf[g][t] = *(const bf16x8*)(wc + (size_t)t * 512);
            }
        }
        __builtin_amdgcn_sched_barrier(0);  // keep all GP loads in flight
#pragma unroll
        for (int g = 0; g < GP; ++g) {
            if (i0 + g < CPS) {
#pragma unroll
                for (int t = 0; t < NG; ++t)
                    acc[t] = __builtin_amdgcn_mfma_f32_16x16x32_bf16(a[g], bf[g][t], acc[t], 0, 0, 0);
            }
        }
    }

    const bool valid = (vt < VT);
    if constexpr (FUSE) {
        unsigned short* yb = (unsigned short*)yout + (size_t)b * V * COUT;
        float sl[NG], ql[NG];
#pragma unroll
        for (int t = 0; t < NG; ++t) { sl[t] = 0.f; ql[t] = 0.f; }
        if (valid) {
#pragma unroll
            for (int r = 0; r < 4; ++r) {
                int v = v0 + quad * 4 + r;  // C/D: row=(lane>>4)*4+r, col=lane&15
                if (v < V) {
#pragma unroll
                    for (int t = 0; t < NG; ++t) {
                        int cout = (ng * NG + t) * 16 + m;
                        float val = acc[t][r];
                        yb[(size_t)v * COUT + cout] = f2b(val);
                        sl[t] += val;
                        ql[t] = fmaf(val, val, ql[t]);
                    }
                }
            }
        }
#pragma unroll
        for (int t = 0; t < NG; ++t) {
            int cout = (ng * NG + t) * 16 + m;
            atomicAdd(&ss[cout], sl[t]);          // LDS only
            atomicAdd(&ss[COUT + cout], ql[t]);
        }
        __syncthreads();
        float* pb = opart + (size_t)blockIdx.x * (2 * COUT);  // distinct slot
        for (int t = tid; t < 2 * COUT; t += 256) pb[t] = ss[t];
    } else {
        float* yb = (float*)yout + (size_t)b * V * COUT;
        if (valid) {
#pragma unroll
            for (int r = 0; r < 4; ++r) {
                int v = v0 + quad * 4 + r;
                if (v < V) {
#pragma unroll
                    for (int t = 0; t < NG; ++t) {
                        int cout = (ng * NG + t) * 16 + m;
                        atomicAdd(&yb[(size_t)v * COUT + cout], acc[t][r]);
                    }
                }
            }
        }
    }
}

// ---------------------------------------------------------------------------
// conv1_1: CIN=4, KC=76 (padded to 3 chunks), COUT=32, NG=2; batch-pinned;
// partial-stats epilogue (no atomics).
// ---------------------------------------------------------------------------
__global__ __launch_bounds__(256) void conv1_mfma(
    const unsigned short* __restrict__ actb, const int* __restrict__ neigh,
    const unsigned short* __restrict__ wp, unsigned short* __restrict__ y,
    float* __restrict__ opart, int V, int perx) {
    __shared__ int shn[4 * 304];
    __shared__ float ss[64];
    const int VT = (V + 15) >> 4;
    const int VT4 = (VT + 3) >> 2;
    const int xcd = blockIdx.x & 7;
    const int b = xcd >> 1;
    const int st = (xcd & 1) * perx + (blockIdx.x >> 3);
    const int tid = threadIdx.x;
    if (st >= VT4) {
        float* pb = opart + (size_t)blockIdx.x * 64;
        for (int t = tid; t < 64; t += 256) pb[t] = 0.f;
        return;
    }
    const int lane = tid & 63;
    const int wib = tid >> 6;
    const int vt = st * 4 + wib;
    const int vtc = vt < VT ? vt : VT - 1;
    const int v0 = vtc * 16;
    const int m = lane & 15, quad = lane >> 4;
    int* sn = shn + wib * 304;
    {
        const int lim = V * 19 - 1;
        for (int t = lane; t < 304; t += 64) {
            int src = v0 * 19 + t;
            sn[t] = neigh[src < lim ? src : lim];
        }
    }
    for (int t = tid; t < 64; t += 256) ss[t] = 0.f;
    __syncthreads();

    const unsigned short* plane = actb + (size_t)b * V * 4;
    const unsigned short* wl = wp + (size_t)lane * 8;

    f32x4 acc[2] = {(f32x4){0.f, 0.f, 0.f, 0.f}, (f32x4){0.f, 0.f, 0.f, 0.f}};
    union { unsigned u[4]; bf16x8 v; } w[3];
    bf16x8 bfr[3][2];
#pragma unroll
    for (int ch = 0; ch < 3; ++ch) {
        int k0 = (ch * 32 + quad * 8) >> 2;
        int k0c = k0 < 18 ? k0 : 18;
        int k1c = k0 + 1 < 18 ? k0 + 1 : 18;
        const unsigned* p0 = (const unsigned*)(plane + (size_t)sn[m * 19 + k0c] * 4);
        const unsigned* p1 = (const unsigned*)(plane + (size_t)sn[m * 19 + k1c] * 4);
        w[ch].u[0] = p0[0]; w[ch].u[1] = p0[1];
        w[ch].u[2] = p1[0]; w[ch].u[3] = p1[1];   // OOB k: weights zero-padded
#pragma unroll
        for (int t = 0; t < 2; ++t)
            bfr[ch][t] = *(const bf16x8*)(wl + (size_t)ch * 1024 + (size_t)t * 512);
    }
    __builtin_amdgcn_sched_barrier(0);
#pragma unroll
    for (int ch = 0; ch < 3; ++ch)
#pragma unroll
        for (int t = 0; t < 2; ++t)
            acc[t] = __builtin_amdgcn_mfma_f32_16x16x32_bf16(w[ch].v, bfr[ch][t], acc[t], 0, 0, 0);

    unsigned short* yb = y + (size_t)b * V * 32;
    float sl[2] = {0.f, 0.f}, ql[2] = {0.f, 0.f};
    if (vt < VT) {
#pragma unroll
        for (int r = 0; r < 4; ++r) {
            int v = v0 + quad * 4 + r;
            if (v < V) {
#pragma unroll
                for (int t = 0; t < 2; ++t) {
                    float val = acc[t][r];
                    yb[(size_t)v * 32 + t * 16 + m] = f2b(val);
                    sl[t] += val;
                    ql[t] = fmaf(val, val, ql[t]);
                }
            }
        }
    }
#pragma unroll
    for (int t = 0; t < 2; ++t) {
        atomicAdd(&ss[t * 16 + m], sl[t]);
        atomicAdd(&ss[32 + t * 16 + m], ql[t]);
    }
    __syncthreads();
    float* pb = opart + (size_t)blockIdx.x * 64;
    for (int t = tid; t < 64; t += 256) pb[t] = ss[t];
}

// ---------------------------------------------------------------------------
// Sum per-block partials: grid.x = 2*C channels; st[c] = sum_b part[b][c]
// ---------------------------------------------------------------------------
__global__ __launch_bounds__(256) void reduce_stats(const float* __restrict__ part,
                                                    float* __restrict__ st, int nblk) {
    __shared__ float red[256];
    int c = blockIdx.x;
    int C2 = gridDim.x;
    float s = 0.f;
    for (int b = threadIdx.x; b < nblk; b += 256) s += part[(size_t)b * C2 + c];
    red[threadIdx.x] = s;
    __syncthreads();
    for (int off = 128; off > 0; off >>= 1) {
        if (threadIdx.x < off) red[threadIdx.x] += red[threadIdx.x + off];
        __syncthreads();
    }
    if (threadIdx.x == 0) st[c] = red[0];
}

// ---------------------------------------------------------------------------
// Per-channel sum / sumsq of fp32 y [rows][C] -> per-XCD replicated stats
// (split-K convs; 480 blocks -> atomic pressure acceptable)
// ---------------------------------------------------------------------------
template <int C>
__global__ __launch_bounds__(256) void stats_kernel(const float* __restrict__ y,
                                                    float* __restrict__ st, int rows) {
    constexpr int LOGC = (C == 32) ? 5 : (C == 64) ? 6 : (C == 128) ? 7 : 8;
    __shared__ float ss[2 * C];
    int tid = threadIdx.x;
    for (int i = tid; i < 2 * C; i += 256) ss[i] = 0.f;
    __syncthreads();
    int c = tid & (C - 1);
    const int rpb = 256 >> LOGC;
    float s = 0.f, q = 0.f;
    for (int r = blockIdx.x * rpb + (tid >> LOGC); r < rows; r += gridDim.x * rpb) {
        float v = y[(size_t)r * C + c];
        s += v;
        q = fmaf(v, v, q);
    }
    atomicAdd(&ss[c], s);
    atomicAdd(&ss[C + c], q);
    __syncthreads();
    float* orep = st + (blockIdx.x & 7) * STREP;
    for (int i = tid; i < 2 * C; i += 256) atomicAdd(&orep[i], ss[i]);
}

// ---------------------------------------------------------------------------
// bnleaky(y) -> bf16 planes. REPL: sum 8 per-XCD replicas; else direct st.
// ---------------------------------------------------------------------------
template <int C, bool BIN, bool REPL>
__global__ __launch_bounds__(256) void finalize_kernel(
    const void* __restrict__ yin, const float* __restrict__ st,
    const float* __restrict__ g, const float* __restrict__ be, float invN,
    unsigned short* __restrict__ out, int total4) {
    __shared__ float la[C], lc[C];
    int tid = threadIdx.x;
    for (int c = tid; c < C; c += 256) {
        float s, q;
        if constexpr (REPL) {
            s = 0.f; q = 0.f;
#pragma unroll
            for (int k = 0; k < 8; ++k) { s += st[k * STREP + c]; q += st[k * STREP + C + c]; }
        } else {
            s = st[c]; q = st[C + c];
        }
        float mu = s * invN;
        float var = fmaf(q, invN, -mu * mu);
        float a = g[c] * rsqrtf(var + 1e-5f);
        la[c] = a;
        lc[c] = fmaf(-mu, a, be[c]);
    }
    __syncthreads();
    int idx = blockIdx.x * 256 + tid;
    if (idx >= total4) return;
    int c0 = (idx * 4) & (C - 1);
    float v0, v1, v2, v3;
    if constexpr (BIN) {
        uint2 d = ((const uint2*)yin)[idx];
        v0 = b2f((unsigned short)(d.x & 0xffff));
        v1 = b2f((unsigned short)(d.x >> 16));
        v2 = b2f((unsigned short)(d.y & 0xffff));
        v3 = b2f((unsigned short)(d.y >> 16));
    } else {
        float4 yv = ((const float4*)yin)[idx];
        v0 = yv.x; v1 = yv.y; v2 = yv.z; v3 = yv.w;
    }
    float o0 = leaky_f(fmaf(la[c0 + 0], v0, lc[c0 + 0]));
    float o1 = leaky_f(fmaf(la[c0 + 1], v1, lc[c0 + 1]));
    float o2 = leaky_f(fmaf(la[c0 + 2], v2, lc[c0 + 2]));
    float o3 = leaky_f(fmaf(la[c0 + 3], v3, lc[c0 + 3]));
    unsigned r0 = (unsigned)f2b(o0) | ((unsigned)f2b(o1) << 16);
    unsigned r1 = (unsigned)f2b(o2) | ((unsigned)f2b(o3) << 16);
    ((uint2*)out)[idx] = make_uint2(r0, r1);
}

// ---------------------------------------------------------------------------
// Mean-pool bf16 planes [B][Vin][C] -> [B][VP][C]; batch-pinned-to-XCD
// ---------------------------------------------------------------------------
template <int C>
__global__ __launch_bounds__(256) void pool_kernel(const unsigned short* __restrict__ in,
                                                   const int* __restrict__ neigh,
                                                   unsigned short* __restrict__ out,
                                                   int Vin, int VP, int perx) {
    constexpr int LOGC4 = (C == 32) ? 3 : (C == 64) ? 4 : 5;
    const int xcd = blockIdx.x & 7;
    const int b = xcd >> 1;
    const int l = (xcd & 1) * perx + (blockIdx.x >> 3);
    int idx = l * 256 + threadIdx.x;
    if (idx >= VP * (C / 4)) return;
    int c4 = idx & ((C / 4) - 1);
    int vp = idx >> LOGC4;
    const unsigned short* pin = in + (size_t)b * Vin * C;
    float a0 = 0.f, a1 = 0.f, a2 = 0.f, a3 = 0.f;
    for (int k = 0; k < 19; ++k) {
        int n = neigh[vp * 19 + k];
        uint2 d = *(const uint2*)(pin + (size_t)n * C + c4 * 4);
        a0 += b2f((unsigned short)(d.x & 0xffff));
        a1 += b2f((unsigned short)(d.x >> 16));
        a2 += b2f((unsigned short)(d.y & 0xffff));
        a3 += b2f((unsigned short)(d.y >> 16));
    }
    const float r = 1.f / 19.f;
    unsigned r0 = (unsigned)f2b(a0 * r) | ((unsigned)f2b(a1 * r) << 16);
    unsigned r1 = (unsigned)f2b(a2 * r) | ((unsigned)f2b(a3 * r) << 16);
    ((uint2*)(out + (size_t)b * VP * C))[idx] = make_uint2(r0, r1);
}

// ---------------------------------------------------------------------------
// FC over bnleaky(y4_2 fp32); stats come from stats_kernel replicas
// ---------------------------------------------------------------------------
__global__ __launch_bounds__(256) void fc_partial(
    const float* __restrict__ y, const float* __restrict__ wfc,
    const float* __restrict__ st, const float* __restrict__ g,
    const float* __restrict__ be, float invN, float* __restrict__ fcacc) {
    __shared__ float la[256], lc[256];
    __shared__ float sh[4];
    int tid = threadIdx.x;
    if (tid < 4) sh[tid] = 0.f;
    {
        int c = tid;
        float s = 0.f, q = 0.f;
#pragma unroll
        for (int k = 0; k < 8; ++k) { s += st[k * STREP + c]; q += st[k * STREP + 256 + c]; }
        float mu = s * invN;
        float var = fmaf(q, invN, -mu * mu);
        float a = g[c] * rsqrtf(var + 1e-5f);
        la[c] = a;
        lc[c] = fmaf(-mu, a, be[c]);
    }
    __syncthreads();
    float p0 = 0.f, p1 = 0.f, p2 = 0.f, p3 = 0.f;
    const int VC = 642 * 256;
    for (int idx = blockIdx.x * 256 + tid; idx < VC; idx += gridDim.x * 256) {
        int c = idx & 255;
        float a = la[c], cc = lc[c];
        float w = wfc[idx];
        p0 = fmaf(w, leaky_f(fmaf(a, y[idx], cc)), p0);
        p1 = fmaf(w, leaky_f(fmaf(a, y[VC + idx], cc)), p1);
        p2 = fmaf(w, leaky_f(fmaf(a, y[2 * VC + idx], cc)), p2);
        p3 = fmaf(w, leaky_f(fmaf(a, y[3 * VC + idx], cc)), p3);
    }
    atomicAdd(&sh[0], p0);
    atomicAdd(&sh[1], p1);
    atomicAdd(&sh[2], p2);
    atomicAdd(&sh[3], p3);
    __syncthreads();
    if (tid < 4) atomicAdd(&fcacc[tid], sh[tid]);
}

__global__ void fc_finalize(const float* __restrict__ acc, const float* __restrict__ m,
                            const float* __restrict__ wm, const float* __restrict__ bm,
                            const float* __restrict__ wfc, const float* __restrict__ bfc,
                            float* __restrict__ out) {
    int b = threadIdx.x;
    if (b < 4) {
        float mv = m[b];
        float s = 0.f;
#pragma unroll
        for (int j = 0; j < 4; ++j) {
            float mm = fmaxf(fmaf(mv, wm[j], bm[j]), 0.f);
            s = fmaf(mm, wfc[642 * 256 + j], s);
        }
        out[b] = acc[b] + s + bfc[0];
    }
}

// ---------------------------------------------------------------------------
// Workspace (bytes): Y/Ybf @0 (21 MB); P @20972544; Q @31458816;
// st @41945088 (128 KB replicas + fcacc); WP @42076176 (5 MB);
// partials @47106064 (657 KB)
// ---------------------------------------------------------------------------
extern "C" void kernel_launch(void* const* d_in, const int* in_sizes, int n_in,
                              void* d_out, int out_size, void* d_ws, size_t ws_size,
                              hipStream_t stream) {
    const float* x = (const float*)d_in[0];
    const float* m = (const float*)d_in[1];
    const int* n0 = (const int*)d_in[2];
    const int* n1 = (const int*)d_in[3];
    const int* n2 = (const int*)d_in[4];
    const int* n3 = (const int*)d_in[5];

    // conv biases cancel exactly through batch-stats BN -> omitted.
    const float* G[8]  = {(const float*)d_in[8],  (const float*)d_in[12],
                          (const float*)d_in[16], (const float*)d_in[20],
                          (const float*)d_in[24], (const float*)d_in[28],
                          (const float*)d_in[32], (const float*)d_in[36]};
    const float* E[8]  = {(const float*)d_in[9],  (const float*)d_in[13],
                          (const float*)d_in[17], (const float*)d_in[21],
                          (const float*)d_in[25], (const float*)d_in[29],
                          (const float*)d_in[33], (const float*)d_in[37]};
    const float* wm  = (const float*)d_in[38];
    const float* bm  = (const float*)d_in[39];
    const float* wfc = (const float*)d_in[40];
    const float* bfc = (const float*)d_in[41];

    char* wsb = (char*)d_ws;
    float* Y = (float*)wsb;                       // fp32 (split convs, levels 3/4)
    unsigned short* Ybf = (unsigned short*)wsb;   // bf16 (fused convs, levels 1/2)
    unsigned short* P = (unsigned short*)(wsb + 20972544);
    unsigned short* Q = (unsigned short*)(wsb + 31458816);
    float* st = (float*)(wsb + 41945088);         // 8 convs x 4096 floats
    float* fcacc = st + 32768;
    unsigned short* WP = (unsigned short*)(wsb + 42076176);
    float* part = (float*)(wsb + 47106064);

    static const int wp_off[8] = {0, 3072, 22528, 61440, 139264, 303104, 614400, 1269760};

    hipMemsetAsync(st, 0, 131088, stream);
    cast_x<<<dim3(641, 4), 256, 0, stream>>>(x, P, 40962);
    prepack_all<<<9824, 256, 0, stream>>>((const float*)d_in[6], (const float*)d_in[10],
                                          (const float*)d_in[14], (const float*)d_in[18],
                                          (const float*)d_in[22], (const float*)d_in[26],
                                          (const float*)d_in[30], (const float*)d_in[34], WP);

    const float iN1 = 1.f / (40962.f * 4.f);
    const float iN2 = 1.f / (10242.f * 4.f);
    const float iN3 = 1.f / (2562.f * 4.f);
    const float iN4 = 1.f / (642.f * 4.f);

    // ---- Level 1 (V=40962, VT=2561, VT4=641) ----
    conv1_mfma<<<2568, 256, 0, stream>>>(P, n0, WP + wp_off[0], Ybf, part, 40962, 321);
    reduce_stats<<<64, 256, 0, stream>>>(part, st + 0 * 4096, 2568);
    finalize_kernel<32, true, false><<<5121, 256, 0, stream>>>(Ybf, st + 0 * 4096, G[0], E[0], iN1, Q, 1310784);
    conv_mfma<32, 32, 2, 19, 1, true><<<2568, 256, 0, stream>>>(
        Q, n0, WP + wp_off[1], Ybf, part, 40962, 321);
    reduce_stats<<<64, 256, 0, stream>>>(part, st + 1 * 4096, 2568);
    finalize_kernel<32, true, false><<<5121, 256, 0, stream>>>(Ybf, st + 1 * 4096, G[1], E[1], iN1, P, 1310784);
    pool_kernel<32><<<1288, 256, 0, stream>>>(P, n0, Q, 40962, 10242, 161);

    // ---- Level 2 (V=10242, VT=641, VT4=161) ----
    conv_mfma<32, 64, 4, 19, 1, true><<<648, 256, 0, stream>>>(
        Q, n1, WP + wp_off[2], Ybf, part, 10242, 81);
    reduce_stats<<<128, 256, 0, stream>>>(part, st + 2 * 4096, 648);
    finalize_kernel<64, true, false><<<2561, 256, 0, stream>>>(Ybf, st + 2 * 4096, G[2], E[2], iN2, P, 655488);
    conv_mfma<64, 64, 4, 38, 1, true><<<648, 256, 0, stream>>>(
        P, n1, WP + wp_off[3], Ybf, part, 10242, 81);
    reduce_stats<<<128, 256, 0, stream>>>(part, st + 3 * 4096, 648);
    finalize_kernel<64, true, false><<<2561, 256, 0, stream>>>(Ybf, st + 3 * 4096, G[3], E[3], iN2, Q, 655488);
    pool_kernel<64><<<648, 256, 0, stream>>>(Q, n1, P, 10242, 2562, 81);

    // ---- Level 3 (V=2562, VT=161, VT4=41) ----
    hipMemsetAsync(Y, 0, 5246976, stream);
    conv_mfma<64, 128, 4, 10, 4, false><<<1312, 256, 0, stream>>>(
        P, n2, WP + wp_off[4], Y, nullptr, 2562, 164);
    stats_kernel<128><<<480, 256, 0, stream>>>(Y, st + 4 * 4096, 10248);
    finalize_kernel<128, false, true><<<1281, 256, 0, stream>>>(Y, st + 4 * 4096, G[4], E[4], iN3, Q, 327936);
    hipMemsetAsync(Y, 0, 5246976, stream);
    conv_mfma<128, 128, 4, 19, 4, false><<<1312, 256, 0, stream>>>(
        Q, n2, WP + wp_off[5], Y, nullptr, 2562, 164);
    stats_kernel<128><<<480, 256, 0, stream>>>(Y, st + 5 * 4096, 10248);
    finalize_kernel<128, false, true><<<1281, 256, 0, stream>>>(Y, st + 5 * 4096, G[5], E[5], iN3, P, 327936);
    pool_kernel<128><<<328, 256, 0, stream>>>(P, n2, Q, 2562, 642, 41);

    // ---- Level 4 (V=642, VT=41, VT4=11) ----
    hipMemsetAsync(Y, 0, 2629632, stream);
    conv_mfma<128, 256, 4, 10, 8, false><<<1408, 256, 0, stream>>>(
        Q, n3, WP + wp_off[6], Y, nullptr, 642, 176);
    stats_kernel<256><<<480, 256, 0, stream>>>(Y, st + 6 * 4096, 2568);
    finalize_kernel<256, false, true><<<642, 256, 0, stream>>>(Y, st + 6 * 4096, G[6], E[6], iN4, P, 164352);
    hipMemsetAsync(Y, 0, 2629632, stream);
    conv_mfma<256, 256, 4, 19, 8, false><<<1408, 256, 0, stream>>>(
        P, n3, WP + wp_off[7], Y, nullptr, 642, 176);
    stats_kernel<256><<<480, 256, 0, stream>>>(Y, st + 7 * 4096, 2568);

    // ---- FC ----
    fc_partial<<<128, 256, 0, stream>>>(Y, wfc, st + 7 * 4096, G[7], E[7], iN4, fcacc);
    fc_finalize<<<1, 64, 0, stream>>>(fcacc, m, wm, bm, wfc, bfc, (float*)d_out);
}

// Round 8
// 476.196 us; speedup vs baseline: 1.0889x; 1.0889x over previous
//
#include <hip/hip_runtime.h>

typedef short bf16x8 __attribute__((ext_vector_type(8)));
typedef float f32x4 __attribute__((ext_vector_type(4)));

#define STREP 512
#define MB 1048576

__device__ __forceinline__ float leaky_f(float z) { return fmaxf(z, 0.2f * z); }
__device__ __forceinline__ unsigned short f2b(float f) {
    unsigned u = __float_as_uint(f);
    return (unsigned short)((u + 0x7fffu + ((u >> 16) & 1u)) >> 16);  // RTNE
}
__device__ __forceinline__ float b2f(unsigned short h) {
    return __uint_as_float(((unsigned)h) << 16);
}

// ---------------------------------------------------------------------------
// x fp32 [V][4ci][4b] -> bf16 [V][4b][4ci]  (batch-interleaved layout)
// ---------------------------------------------------------------------------
__global__ __launch_bounds__(256) void cast_x(const float* __restrict__ x,
                                              unsigned short* __restrict__ out, int total) {
    int idx = blockIdx.x * 256 + threadIdx.x;
    if (idx >= total) return;
    int v = idx >> 4, b = (idx >> 2) & 3, ci = idx & 3;
    out[idx] = f2b(x[(size_t)v * 16 + ci * 4 + b]);
}

// ---------------------------------------------------------------------------
// All 8 weight prepacks in ONE launch (B-fragment order, zero-padded chunks)
// ---------------------------------------------------------------------------
__global__ __launch_bounds__(256) void prepack_all(
    const float* __restrict__ w0, const float* __restrict__ w1,
    const float* __restrict__ w2, const float* __restrict__ w3,
    const float* __restrict__ w4, const float* __restrict__ w5,
    const float* __restrict__ w6, const float* __restrict__ w7,
    unsigned short* __restrict__ WP) {
    int gid = blockIdx.x * 256 + threadIdx.x;  // < 2514944
    const float* W;
    int base, KC, NT;
    if (gid < 3072)        { W = w0; base = 0;       KC = 76;   NT = 2; }
    else if (gid < 22528)  { W = w1; base = 3072;    KC = 608;  NT = 2; }
    else if (gid < 61440)  { W = w2; base = 22528;   KC = 608;  NT = 4; }
    else if (gid < 139264) { W = w3; base = 61440;   KC = 1216; NT = 4; }
    else if (gid < 303104) { W = w4; base = 139264;  KC = 1216; NT = 8; }
    else if (gid < 614400) { W = w5; base = 303104;  KC = 2432; NT = 8; }
    else if (gid < 1269760){ W = w6; base = 614400;  KC = 2432; NT = 16; }
    else                   { W = w7; base = 1269760; KC = 4864; NT = 16; }
    int idx = gid - base;
    int j = idx & 7, lane = (idx >> 3) & 63, q = idx >> 9;
    int nt = q % NT, chunk = q / NT;
    int kc = chunk * 32 + (lane >> 4) * 8 + j;
    int cout = nt * 16 + (lane & 15);
    float v = (kc < KC) ? W[(size_t)cout * KC + kc] : 0.f;
    WP[gid] = f2b(v);
}

// ---------------------------------------------------------------------------
// Pair-tile MFMA conv on [V][4][C] bf16. M-tile = 8 vertices x 2 batches
// (pair p = xcd>>2, pinned: 4 XCDs per pair -> gather lines shared across the
// 2 batches and pair working set ~fits one XCD L2). Block = 4 waves = 4 tiles.
// BN: apply prev-layer bnleaky to gathered A-fragments (coeffs in LDS).
// FUSE: raw bf16 store + per-block partial stats. !FUSE: split-K atomicAdd.
// ---------------------------------------------------------------------------
template <int CIN, int COUT, int NG, int CPS, int SPLIT, bool FUSE, bool BN>
__global__ __launch_bounds__(256, 4) void conv_mfma(
    const unsigned short* __restrict__ act, const int* __restrict__ neigh,
    const unsigned short* __restrict__ wp, void* __restrict__ yout,
    float* __restrict__ opart, const float* __restrict__ pstats,
    const float* __restrict__ pg, const float* __restrict__ pe,
    float invN, int V, int perx) {
    constexpr int LOGC = (CIN == 32) ? 5 : (CIN == 64) ? 6 : (CIN == 128) ? 7 : 8;
    constexpr int NT = COUT / 16;
    constexpr int NGRP = NT / NG;
    constexpr int GP = (NG >= 4) ? 3 : ((CPS < 6) ? CPS : 6);
    __shared__ int shn[4 * 152];
    __shared__ float ss[FUSE ? 2 * COUT : 1];
    __shared__ float2 lac[BN ? CIN : 1];
    const int T8 = (V + 7) >> 3;
    const int ST = (T8 + 3) >> 2;
    const int L = ST * NGRP * SPLIT;
    const int xcd = blockIdx.x & 7;
    const int p = xcd >> 2;
    const int li = (xcd & 3) * perx + (blockIdx.x >> 3);
    const int tid = threadIdx.x;
    if (li >= L) {
        if constexpr (FUSE) {
            float* pb = opart + (size_t)blockIdx.x * (2 * COUT);
            for (int t = tid; t < 2 * COUT; t += 256) pb[t] = 0.f;
        }
        return;
    }
    const int sp = li % SPLIT;
    const int t1 = li / SPLIT;
    const int ng = t1 % NGRP;
    const int stile = t1 / NGRP;
    const int lane = tid & 63, wib = tid >> 6;
    const int v0 = (stile * 4 + wib) * 8;
    const int m = lane & 15, quad = lane >> 4;
    const int vi = m >> 1, bb = m & 1;
    int* sn = shn + wib * 152;
    {
        const int lim = V * 19 - 1;
        for (int t = lane; t < 152; t += 64) {
            int src = v0 * 19 + t;
            sn[t] = neigh[src < lim ? src : lim];
        }
    }
    if constexpr (BN) {
        for (int c = tid; c < CIN; c += 256) {
            float s = pstats[c], q = pstats[CIN + c];
            float mu = s * invN;
            float var = fmaf(q, invN, -mu * mu);
            float a = pg[c] * rsqrtf(var + 1e-5f);
            lac[c] = make_float2(a, fmaf(-mu, a, pe[c]));
        }
    }
    if constexpr (FUSE) {
        for (int t = tid; t < 2 * COUT; t += 256) ss[t] = 0.f;
    }
    __syncthreads();

    const unsigned short* wl = wp + ((size_t)(ng * NG) * 64 + lane) * 8;
    const int c0 = sp * CPS;
    const int boff = p * 2 + bb;

    f32x4 acc[NG];
#pragma unroll
    for (int t = 0; t < NG; ++t) acc[t] = (f32x4){0.f, 0.f, 0.f, 0.f};

#pragma unroll
    for (int i0 = 0; i0 < CPS; i0 += GP) {
        bf16x8 a[GP];
        bf16x8 bf[GP][NG];
        int cia[GP];
#pragma unroll
        for (int g = 0; g < GP; ++g) {
            if (i0 + g < CPS) {
                const int ch = c0 + i0 + g;
                int k_nb = (ch * 32) >> LOGC;
                k_nb = k_nb < 18 ? k_nb : 18;   // zero-padded chunk clamp
                const int ci = ((ch * 32) & (CIN - 1)) + quad * 8;
                cia[g] = ci;
                const int n = sn[vi * 19 + k_nb];
                a[g] = *(const bf16x8*)(act + ((size_t)n * 4 + boff) * CIN + ci);
                const unsigned short* wc = wl + (size_t)ch * NT * 512;
#pragma unroll
                for (int t = 0; t < NG; ++t)
                    bf[g][t] = *(const bf16x8*)(wc + (size_t)t * 512);
            }
        }
        __builtin_amdgcn_sched_barrier(0);
        if constexpr (BN) {
#pragma unroll
            for (int g = 0; g < GP; ++g) {
                if (i0 + g < CPS) {
                    bf16x8 r = a[g];
#pragma unroll
                    for (int j = 0; j < 8; ++j) {
                        float2 t2 = lac[cia[g] + j];
                        r[j] = (short)f2b(leaky_f(fmaf(b2f((unsigned short)r[j]), t2.x, t2.y)));
                    }
                    a[g] = r;
                }
            }
        }
#pragma unroll
        for (int g = 0; g < GP; ++g) {
            if (i0 + g < CPS) {
#pragma unroll
                for (int t = 0; t < NG; ++t)
                    acc[t] = __builtin_amdgcn_mfma_f32_16x16x32_bf16(a[g], bf[g][t], acc[t], 0, 0, 0);
            }
        }
    }

    // C/D row = quad*4+r -> v = v0 + quad*2 + (r>>1), batch = p*2 + (r&1)
    if constexpr (FUSE) {
        unsigned short* y = (unsigned short*)yout;
        float sl[NG], ql[NG];
#pragma unroll
        for (int t = 0; t < NG; ++t) { sl[t] = 0.f; ql[t] = 0.f; }
#pragma unroll
        for (int r = 0; r < 4; ++r) {
            int v = v0 + quad * 2 + (r >> 1);
            if (v < V) {
                size_t row = ((size_t)v * 4 + p * 2 + (r & 1)) * COUT;
#pragma unroll
                for (int t = 0; t < NG; ++t) {
                    int cout = (ng * NG + t) * 16 + m;
                    float val = acc[t][r];
                    y[row + cout] = f2b(val);
                    sl[t] += val;
                    ql[t] = fmaf(val, val, ql[t]);
                }
            }
        }
#pragma unroll
        for (int t = 0; t < NG; ++t) {
            int cout = (ng * NG + t) * 16 + m;
            atomicAdd(&ss[cout], sl[t]);
            atomicAdd(&ss[COUT + cout], ql[t]);
        }
        __syncthreads();
        float* pb = opart + (size_t)blockIdx.x * (2 * COUT);
        for (int t = tid; t < 2 * COUT; t += 256) pb[t] = ss[t];
    } else {
        float* y = (float*)yout;
#pragma unroll
        for (int r = 0; r < 4; ++r) {
            int v = v0 + quad * 2 + (r >> 1);
            if (v < V) {
                size_t row = ((size_t)v * 4 + p * 2 + (r & 1)) * COUT;
#pragma unroll
                for (int t = 0; t < NG; ++t)
                    atomicAdd(&y[row + (ng * NG + t) * 16 + m], acc[t][r]);
            }
        }
    }
}

// ---------------------------------------------------------------------------
// conv1_1: CIN=4, quad-tile (4 vertices x 4 batches), unpinned. Raw bf16 out
// + partial stats. Input X0 [V][4b][4ci] bf16.
// ---------------------------------------------------------------------------
__global__ __launch_bounds__(256) void conv1_mfma(
    const unsigned short* __restrict__ act, const int* __restrict__ neigh,
    const unsigned short* __restrict__ wp, unsigned short* __restrict__ y,
    float* __restrict__ opart, int V) {
    __shared__ int shn[4 * 76];
    __shared__ float ss[64];
    const int tid = threadIdx.x;
    const int lane = tid & 63, wib = tid >> 6;
    const int v0 = (blockIdx.x * 4 + wib) * 4;
    const int m = lane & 15, quad = lane >> 4;
    int* sn = shn + wib * 76;
    {
        const int lim = V * 19 - 1;
        for (int t = lane; t < 76; t += 64) {
            int src = v0 * 19 + t;
            sn[t] = neigh[src < lim ? src : lim];
        }
    }
    for (int t = tid; t < 64; t += 256) ss[t] = 0.f;
    __syncthreads();

    const unsigned short* wl = wp + (size_t)lane * 8;
    const int b = m & 3, vq = m >> 2;

    f32x4 acc[2] = {(f32x4){0.f, 0.f, 0.f, 0.f}, (f32x4){0.f, 0.f, 0.f, 0.f}};
    union { unsigned u[4]; bf16x8 v; } w[3];
    bf16x8 bfr[3][2];
#pragma unroll
    for (int ch = 0; ch < 3; ++ch) {
        int k0 = (ch * 32 + quad * 8) >> 2;
        int k0c = k0 < 18 ? k0 : 18;
        int k1c = k0 + 1 < 18 ? k0 + 1 : 18;
        const unsigned* p0 = (const unsigned*)(act + ((size_t)sn[vq * 19 + k0c] * 4 + b) * 4);
        const unsigned* p1 = (const unsigned*)(act + ((size_t)sn[vq * 19 + k1c] * 4 + b) * 4);
        w[ch].u[0] = p0[0]; w[ch].u[1] = p0[1];
        w[ch].u[2] = p1[0]; w[ch].u[3] = p1[1];   // OOB k: weights zero-padded
#pragma unroll
        for (int t = 0; t < 2; ++t)
            bfr[ch][t] = *(const bf16x8*)(wl + (size_t)ch * 1024 + (size_t)t * 512);
    }
    __builtin_amdgcn_sched_barrier(0);
#pragma unroll
    for (int ch = 0; ch < 3; ++ch)
#pragma unroll
        for (int t = 0; t < 2; ++t)
            acc[t] = __builtin_amdgcn_mfma_f32_16x16x32_bf16(w[ch].v, bfr[ch][t], acc[t], 0, 0, 0);

    // C/D row = quad*4+r -> v = v0 + quad, batch = r
    float sl[2] = {0.f, 0.f}, ql[2] = {0.f, 0.f};
    int v = v0 + quad;
    if (v < V) {
        size_t rb = (size_t)v * 4 * 32;
#pragma unroll
        for (int r = 0; r < 4; ++r) {
#pragma unroll
            for (int t = 0; t < 2; ++t) {
                float val = acc[t][r];
                y[rb + (size_t)r * 32 + t * 16 + m] = f2b(val);
                sl[t] += val;
                ql[t] = fmaf(val, val, ql[t]);
            }
        }
    }
#pragma unroll
    for (int t = 0; t < 2; ++t) {
        atomicAdd(&ss[t * 16 + m], sl[t]);
        atomicAdd(&ss[32 + t * 16 + m], ql[t]);
    }
    __syncthreads();
    float* pb = opart + (size_t)blockIdx.x * 64;
    for (int t = tid; t < 64; t += 256) pb[t] = ss[t];
}

// ---------------------------------------------------------------------------
// Sum per-block partials: grid.x = 2*C; st[c] = sum_b part[b][c]
// ---------------------------------------------------------------------------
__global__ __launch_bounds__(256) void reduce_stats(const float* __restrict__ part,
                                                    float* __restrict__ st, int nblk) {
    __shared__ float red[256];
    int c = blockIdx.x;
    int C2 = gridDim.x;
    float s = 0.f;
    for (int b = threadIdx.x; b < nblk; b += 256) s += part[(size_t)b * C2 + c];
    red[threadIdx.x] = s;
    __syncthreads();
    for (int off = 128; off > 0; off >>= 1) {
        if (threadIdx.x < off) red[threadIdx.x] += red[threadIdx.x + off];
        __syncthreads();
    }
    if (threadIdx.x == 0) st[c] = red[0];
}

// ---------------------------------------------------------------------------
// Per-channel sum/sumsq of fp32 y [rows][C] -> per-XCD replicated stats
// ---------------------------------------------------------------------------
template <int C>
__global__ __launch_bounds__(256) void stats_kernel(const float* __restrict__ y,
                                                    float* __restrict__ st, int rows) {
    constexpr int LOGC = (C == 128) ? 7 : 8;
    __shared__ float ss[2 * C];
    int tid = threadIdx.x;
    for (int i = tid; i < 2 * C; i += 256) ss[i] = 0.f;
    __syncthreads();
    int c = tid & (C - 1);
    const int rpb = 256 >> LOGC;
    float s = 0.f, q = 0.f;
    for (int r = blockIdx.x * rpb + (tid >> LOGC); r < rows; r += gridDim.x * rpb) {
        float v = y[(size_t)r * C + c];
        s += v;
        q = fmaf(v, v, q);
    }
    atomicAdd(&ss[c], s);
    atomicAdd(&ss[C + c], q);
    __syncthreads();
    float* orep = st + (blockIdx.x & 7) * STREP;
    for (int i = tid; i < 2 * C; i += 256) atomicAdd(&orep[i], ss[i]);
}

// ---------------------------------------------------------------------------
// bnleaky(fp32 y, replicated stats) -> finished bf16 (split-conv outputs)
// ---------------------------------------------------------------------------
template <int C>
__global__ __launch_bounds__(256) void finalize_kernel(
    const float* __restrict__ yin, const float* __restrict__ st,
    const float* __restrict__ g, const float* __restrict__ be, float invN,
    unsigned short* __restrict__ out, int total4) {
    __shared__ float la[C], lc[C];
    int tid = threadIdx.x;
    for (int c = tid; c < C; c += 256) {
        float s = 0.f, q = 0.f;
#pragma unroll
        for (int k = 0; k < 8; ++k) { s += st[k * STREP + c]; q += st[k * STREP + C + c]; }
        float mu = s * invN;
        float var = fmaf(q, invN, -mu * mu);
        float a = g[c] * rsqrtf(var + 1e-5f);
        la[c] = a;
        lc[c] = fmaf(-mu, a, be[c]);
    }
    __syncthreads();
    int idx = blockIdx.x * 256 + tid;
    if (idx >= total4) return;
    int c0 = (idx * 4) & (C - 1);
    float4 yv = ((const float4*)yin)[idx];
    float o0 = leaky_f(fmaf(la[c0 + 0], yv.x, lc[c0 + 0]));
    float o1 = leaky_f(fmaf(la[c0 + 1], yv.y, lc[c0 + 1]));
    float o2 = leaky_f(fmaf(la[c0 + 2], yv.z, lc[c0 + 2]));
    float o3 = leaky_f(fmaf(la[c0 + 3], yv.w, lc[c0 + 3]));
    unsigned r0 = (unsigned)f2b(o0) | ((unsigned)f2b(o1) << 16);
    unsigned r1 = (unsigned)f2b(o2) | ((unsigned)f2b(o3) << 16);
    ((uint2*)out)[idx] = make_uint2(r0, r1);
}

// ---------------------------------------------------------------------------
// Mean-pool on [Vin][4][C] -> [VP][4][C]. BN: apply producer bnleaky (plain
// stats) at gather. Output finished bf16.
// ---------------------------------------------------------------------------
template <int C, bool BN>
__global__ __launch_bounds__(256) void pool_kernel(
    const unsigned short* __restrict__ in, const int* __restrict__ neigh,
    const float* __restrict__ pstats, const float* __restrict__ pg,
    const float* __restrict__ pe, float invN,
    unsigned short* __restrict__ out, int total) {
    constexpr int LC4 = (C == 32) ? 3 : (C == 64) ? 4 : 5;
    __shared__ float2 lac[BN ? C : 1];
    int tid = threadIdx.x;
    if constexpr (BN) {
        for (int c = tid; c < C; c += 256) {
            float s = pstats[c], q = pstats[C + c];
            float mu = s * invN;
            float var = fmaf(q, invN, -mu * mu);
            float a = pg[c] * rsqrtf(var + 1e-5f);
            lac[c] = make_float2(a, fmaf(-mu, a, pe[c]));
        }
        __syncthreads();
    }
    int idx = blockIdx.x * 256 + tid;
    if (idx >= total) return;
    int c4 = idx & ((C / 4) - 1);
    int b = (idx >> LC4) & 3;
    int vp = idx >> (LC4 + 2);
    float a0 = 0.f, a1 = 0.f, a2 = 0.f, a3 = 0.f;
    for (int k = 0; k < 19; ++k) {
        int n = neigh[vp * 19 + k];
        uint2 d = *(const uint2*)(in + ((size_t)n * 4 + b) * C + c4 * 4);
        float f0 = b2f((unsigned short)(d.x & 0xffff));
        float f1 = b2f((unsigned short)(d.x >> 16));
        float f2 = b2f((unsigned short)(d.y & 0xffff));
        float f3 = b2f((unsigned short)(d.y >> 16));
        if constexpr (BN) {
            float2 t0 = lac[c4 * 4 + 0], t1 = lac[c4 * 4 + 1];
            float2 t2 = lac[c4 * 4 + 2], t3 = lac[c4 * 4 + 3];
            f0 = leaky_f(fmaf(f0, t0.x, t0.y));
            f1 = leaky_f(fmaf(f1, t1.x, t1.y));
            f2 = leaky_f(fmaf(f2, t2.x, t2.y));
            f3 = leaky_f(fmaf(f3, t3.x, t3.y));
        }
        a0 += f0; a1 += f1; a2 += f2; a3 += f3;
    }
    const float r = 1.f / 19.f;
    unsigned r0 = (unsigned)f2b(a0 * r) | ((unsigned)f2b(a1 * r) << 16);
    unsigned r1 = (unsigned)f2b(a2 * r) | ((unsigned)f2b(a3 * r) << 16);
    ((uint2*)out)[idx] = make_uint2(r0, r1);
}

// ---------------------------------------------------------------------------
// FC over bnleaky(y4_2 fp32 [642][4][256], replicated stats)
// ---------------------------------------------------------------------------
__global__ __launch_bounds__(256) void fc_partial(
    const float* __restrict__ y, const float* __restrict__ wfc,
    const float* __restrict__ st, const float* __restrict__ g,
    const float* __restrict__ be, float invN, float* __restrict__ fcacc) {
    __shared__ float la[256], lc[256];
    __shared__ float sh[4];
    int tid = threadIdx.x;
    if (tid < 4) sh[tid] = 0.f;
    {
        int c = tid;
        float s = 0.f, q = 0.f;
#pragma unroll
        for (int k = 0; k < 8; ++k) { s += st[k * STREP + c]; q += st[k * STREP + 256 + c]; }
        float mu = s * invN;
        float var = fmaf(q, invN, -mu * mu);
        float a = g[c] * rsqrtf(var + 1e-5f);
        la[c] = a;
        lc[c] = fmaf(-mu, a, be[c]);
    }
    __syncthreads();
    float p0 = 0.f, p1 = 0.f, p2 = 0.f, p3 = 0.f;
    const int VC = 642 * 256;
    for (int idx = blockIdx.x * 256 + tid; idx < VC; idx += gridDim.x * 256) {
        int c = idx & 255;
        float a = la[c], cc = lc[c];
        float w = wfc[idx];
        size_t base = ((size_t)(idx >> 8) << 10) + c;   // v*1024 + c
        p0 = fmaf(w, leaky_f(fmaf(a, y[base], cc)), p0);
        p1 = fmaf(w, leaky_f(fmaf(a, y[base + 256], cc)), p1);
        p2 = fmaf(w, leaky_f(fmaf(a, y[base + 512], cc)), p2);
        p3 = fmaf(w, leaky_f(fmaf(a, y[base + 768], cc)), p3);
    }
    atomicAdd(&sh[0], p0);
    atomicAdd(&sh[1], p1);
    atomicAdd(&sh[2], p2);
    atomicAdd(&sh[3], p3);
    __syncthreads();
    if (tid < 4) atomicAdd(&fcacc[tid], sh[tid]);
}

__global__ void fc_finalize(const float* __restrict__ acc, const float* __restrict__ m,
                            const float* __restrict__ wm, const float* __restrict__ bm,
                            const float* __restrict__ wfc, const float* __restrict__ bfc,
                            float* __restrict__ out) {
    int b = threadIdx.x;
    if (b < 4) {
        float mv = m[b];
        float s = 0.f;
#pragma unroll
        for (int j = 0; j < 4; ++j) {
            float mm = fmaxf(fmaf(mv, wm[j], bm[j]), 0.f);
            s = fmaf(mm, wfc[642 * 256 + j], s);
        }
        out[b] = acc[b] + s + bfc[0];
    }
}

extern "C" void kernel_launch(void* const* d_in, const int* in_sizes, int n_in,
                              void* d_out, int out_size, void* d_ws, size_t ws_size,
                              hipStream_t stream) {
    const float* x = (const float*)d_in[0];
    const float* m = (const float*)d_in[1];
    const int* n0 = (const int*)d_in[2];
    const int* n1 = (const int*)d_in[3];
    const int* n2 = (const int*)d_in[4];
    const int* n3 = (const int*)d_in[5];

    // conv biases cancel exactly through batch-stats BN -> omitted.
    const float* G[8]  = {(const float*)d_in[8],  (const float*)d_in[12],
                          (const float*)d_in[16], (const float*)d_in[20],
                          (const float*)d_in[24], (const float*)d_in[28],
                          (const float*)d_in[32], (const float*)d_in[36]};
    const float* E[8]  = {(const float*)d_in[9],  (const float*)d_in[13],
                          (const float*)d_in[17], (const float*)d_in[21],
                          (const float*)d_in[25], (const float*)d_in[29],
                          (const float*)d_in[33], (const float*)d_in[37]};
    const float* wm  = (const float*)d_in[38];
    const float* bm  = (const float*)d_in[39];
    const float* wfc = (const float*)d_in[40];
    const float* bfc = (const float*)d_in[41];

    char* wsb = (char*)d_ws;
    unsigned short* X0  = (unsigned short*)(wsb + 0 * MB);
    unsigned short* Y1  = (unsigned short*)(wsb + 2 * MB);   // raw conv1_1 out
    unsigned short* Y2  = (unsigned short*)(wsb + 13 * MB);  // raw conv1_2 out
    unsigned short* P1  = (unsigned short*)(wsb + 24 * MB);  // finished pool1
    unsigned short* Y21 = (unsigned short*)(wsb + 27 * MB);  // raw conv2_1
    unsigned short* Y22 = (unsigned short*)(wsb + 33 * MB);  // raw conv2_2
    unsigned short* P2  = (unsigned short*)(wsb + 39 * MB);  // finished pool2
    unsigned short* WP  = (unsigned short*)(wsb + 41 * MB);
    float* part = (float*)(wsb + 47 * MB);
    float* Z31  = (float*)(wsb + 49 * MB);                   // zeroed
    float* Z32  = (float*)(wsb + 55 * MB);                   // zeroed
    float* Z41  = (float*)(wsb + 61 * MB);                   // zeroed
    float* Z42  = (float*)(wsb + 64 * MB);                   // zeroed
    float* st   = (float*)(wsb + 67 * MB);                   // zeroed (8x4096)
    float* fcacc = (float*)(wsb + 67 * MB + 131072);         // zeroed
    unsigned short* F31 = (unsigned short*)(wsb + 68 * MB);
    unsigned short* F32 = (unsigned short*)(wsb + 71 * MB);
    unsigned short* P3  = (unsigned short*)(wsb + 74 * MB);
    unsigned short* F41 = (unsigned short*)(wsb + 75 * MB);

    static const int wp_off[8] = {0, 3072, 22528, 61440, 139264, 303104, 614400, 1269760};

    const float iN1 = 1.f / (40962.f * 4.f);
    const float iN2 = 1.f / (10242.f * 4.f);
    const float iN3 = 1.f / (2562.f * 4.f);
    const float iN4 = 1.f / (642.f * 4.f);

    // one memset covers Z31..Z42 + st + fcacc
    hipMemsetAsync(wsb + 49 * MB, 0, 18 * MB + 131072 + 16, stream);
    cast_x<<<2561, 256, 0, stream>>>(x, X0, 40962 * 16);
    prepack_all<<<9824, 256, 0, stream>>>((const float*)d_in[6], (const float*)d_in[10],
                                          (const float*)d_in[14], (const float*)d_in[18],
                                          (const float*)d_in[22], (const float*)d_in[26],
                                          (const float*)d_in[30], (const float*)d_in[34], WP);

    // ---- Level 1 (V=40962) ----
    conv1_mfma<<<2561, 256, 0, stream>>>(X0, n0, WP + wp_off[0], Y1, part, 40962);
    reduce_stats<<<64, 256, 0, stream>>>(part, st + 0 * 4096, 2561);
    // conv1_2: pair tiles T8=5121, ST=1281, perx=321, grid=2568
    conv_mfma<32, 32, 2, 19, 1, true, true><<<2568, 256, 0, stream>>>(
        Y1, n0, WP + wp_off[1], Y2, part, st + 0 * 4096, G[0], E[0], iN1, 40962, 321);
    reduce_stats<<<64, 256, 0, stream>>>(part, st + 1 * 4096, 2568);
    pool_kernel<32, true><<<1281, 256, 0, stream>>>(Y2, n0, st + 1 * 4096, G[1], E[1], iN1,
                                                    P1, 10242 * 4 * 8);

    // ---- Level 2 (V=10242) ----  T8=1281, ST=321, perx=81, grid=648
    conv_mfma<32, 64, 4, 19, 1, true, false><<<648, 256, 0, stream>>>(
        P1, n1, WP + wp_off[2], Y21, part, nullptr, nullptr, nullptr, 0.f, 10242, 81);
    reduce_stats<<<128, 256, 0, stream>>>(part, st + 2 * 4096, 648);
    conv_mfma<64, 64, 4, 38, 1, true, true><<<648, 256, 0, stream>>>(
        Y21, n1, WP + wp_off[3], Y22, part, st + 2 * 4096, G[2], E[2], iN2, 10242, 81);
    reduce_stats<<<128, 256, 0, stream>>>(part, st + 3 * 4096, 648);
    pool_kernel<64, true><<<641, 256, 0, stream>>>(Y22, n1, st + 3 * 4096, G[3], E[3], iN2,
                                                   P2, 2562 * 4 * 16);

    // ---- Level 3 (V=2562) ----  T8=321, ST=81, NGRP=2, SPLIT=4 -> L=648, perx=162, grid=1296
    conv_mfma<64, 128, 4, 10, 4, false, false><<<1296, 256, 0, stream>>>(
        P2, n2, WP + wp_off[4], Z31, nullptr, nullptr, nullptr, nullptr, 0.f, 2562, 162);
    stats_kernel<128><<<480, 256, 0, stream>>>(Z31, st + 4 * 4096, 10248);
    finalize_kernel<128><<<1281, 256, 0, stream>>>(Z31, st + 4 * 4096, G[4], E[4], iN3,
                                                   F31, 327936);
    conv_mfma<128, 128, 4, 19, 4, false, false><<<1296, 256, 0, stream>>>(
        F31, n2, WP + wp_off[5], Z32, nullptr, nullptr, nullptr, nullptr, 0.f, 2562, 162);
    stats_kernel<128><<<480, 256, 0, stream>>>(Z32, st + 5 * 4096, 10248);
    finalize_kernel<128><<<1281, 256, 0, stream>>>(Z32, st + 5 * 4096, G[5], E[5], iN3,
                                                   F32, 327936);
    pool_kernel<128, false><<<321, 256, 0, stream>>>(F32, n2, nullptr, nullptr, nullptr, 0.f,
                                                     P3, 642 * 4 * 32);

    // ---- Level 4 (V=642) ----  T8=81, ST=21, NGRP=4, SPLIT=8 -> L=672, perx=168, grid=1344
    conv_mfma<128, 256, 4, 10, 8, false, false><<<1344, 256, 0, stream>>>(
        P3, n3, WP + wp_off[6], Z41, nullptr, nullptr, nullptr, nullptr, 0.f, 642, 168);
    stats_kernel<256><<<480, 256, 0, stream>>>(Z41, st + 6 * 4096, 2568);
    finalize_kernel<256><<<642, 256, 0, stream>>>(Z41, st + 6 * 4096, G[6], E[6], iN4,
                                                  F41, 164352);
    conv_mfma<256, 256, 4, 19, 8, false, false><<<1344, 256, 0, stream>>>(
        F41, n3, WP + wp_off[7], Z42, nullptr, nullptr, nullptr, nullptr, 0.f, 642, 168);
    stats_kernel<256><<<480, 256, 0, stream>>>(Z42, st + 7 * 4096, 2568);

    // ---- FC ----
    fc_partial<<<128, 256, 0, stream>>>(Z42, wfc, st + 7 * 4096, G[7], E[7], iN4, fcacc);
    fc_finalize<<<1, 64, 0, stream>>>(fcacc, m, wm, bm, wfc, bfc, (float*)d_out);
}